// Round 1
// baseline (3298.738 us; speedup 1.0000x reference)
//
#include <hip/hip_runtime.h>
#include <math.h>
#include <stdint.h>

#define GIN_DIM 512
#define GHID_DIM 512
#define GOUT_DIM 64
#define GHOP 10

// ---------------- CSR build ----------------

__global__ void k_count(const int* __restrict__ row, int* __restrict__ cnt, int E) {
  int e = blockIdx.x * blockDim.x + threadIdx.x;
  if (e < E) atomicAdd(&cnt[row[e]], 1);
}

__global__ __launch_bounds__(1024) void k_scan(int* __restrict__ rp, int* __restrict__ nxt, int n) {
  __shared__ int sums[1024];
  int tid = threadIdx.x;
  int chunk = (n + 1023) >> 10;
  int b = tid * chunk;
  int e = min(b + chunk, n);
  int s = 0;
  for (int i = b; i < e; ++i) s += rp[i];
  sums[tid] = s;
  __syncthreads();
  for (int off = 1; off < 1024; off <<= 1) {
    int o = (tid >= off) ? sums[tid - off] : 0;
    __syncthreads();
    sums[tid] += o;
    __syncthreads();
  }
  int run = sums[tid] - s;  // exclusive base
  for (int i = b; i < e; ++i) {
    int c = rp[i];
    rp[i] = run;
    nxt[i] = run;
    run += c;
  }
  if (tid == 1023) rp[n] = sums[1023];
}

__global__ void k_scatter(const int* __restrict__ row, const int* __restrict__ col,
                          const float* __restrict__ ew, int* __restrict__ nxt,
                          int* __restrict__ cs, float* __restrict__ wsrt, int E) {
  int e = blockIdx.x * blockDim.x + threadIdx.x;
  if (e < E) {
    int r = row[e];
    int p = atomicAdd(&nxt[r], 1);
    cs[p] = col[e];
    wsrt[p] = ew[e];
  }
}

// ---------------- GEMM1: h_chunk = relu(x @ W1[:, cbase:cbase+128] + b1) ----------------
// BM=128, BN=128, BK=32, 256 threads, 8x8 frags.

__global__ __launch_bounds__(256) void k_gemm1(const float* __restrict__ x,
                                               const float* __restrict__ w1,
                                               const float* __restrict__ b1,
                                               float* __restrict__ h, int n, int cbase) {
  __shared__ float xs[32][128];
  __shared__ float wsh[32][128];
  int tid = threadIdx.x;
  int tx = tid & 15, ty = tid >> 4;
  int rowbase = blockIdx.x * 128;
  float acc[8][8] = {};

  int sr = tid >> 1;                 // x stage: row 0..127
  int sh = (tid & 1) * 16;           // 16 floats per thread
  int wk = tid >> 3;                 // w1 stage: k 0..31
  int wc = (tid & 7) * 16;           // 16 floats per thread
  int gxr = rowbase + sr;

  for (int ks = 0; ks < GIN_DIM; ks += 32) {
    if (gxr < n) {
      const float* px = x + (size_t)gxr * GIN_DIM + ks + sh;
#pragma unroll
      for (int q = 0; q < 4; ++q) {
        float4 v = *(const float4*)(px + q * 4);
        xs[sh + q * 4 + 0][sr] = v.x;
        xs[sh + q * 4 + 1][sr] = v.y;
        xs[sh + q * 4 + 2][sr] = v.z;
        xs[sh + q * 4 + 3][sr] = v.w;
      }
    } else {
#pragma unroll
      for (int q = 0; q < 16; ++q) xs[sh + q][sr] = 0.f;
    }
    const float* pw = w1 + (size_t)(ks + wk) * GHID_DIM + cbase + wc;
#pragma unroll
    for (int q = 0; q < 4; ++q) *(float4*)&wsh[wk][wc + q * 4] = *(const float4*)(pw + q * 4);
    __syncthreads();

#pragma unroll
    for (int kk = 0; kk < 32; ++kk) {
      float4 a0 = *(const float4*)&xs[kk][ty * 8];
      float4 a1 = *(const float4*)&xs[kk][ty * 8 + 4];
      float4 b0 = *(const float4*)&wsh[kk][tx * 8];
      float4 b1v = *(const float4*)&wsh[kk][tx * 8 + 4];
      float a[8] = {a0.x, a0.y, a0.z, a0.w, a1.x, a1.y, a1.z, a1.w};
      float bb[8] = {b0.x, b0.y, b0.z, b0.w, b1v.x, b1v.y, b1v.z, b1v.w};
#pragma unroll
      for (int i = 0; i < 8; ++i)
#pragma unroll
        for (int j = 0; j < 8; ++j) acc[i][j] = fmaf(a[i], bb[j], acc[i][j]);
    }
    __syncthreads();
  }

  float4 bb0 = *(const float4*)&b1[cbase + tx * 8];
  float4 bb1 = *(const float4*)&b1[cbase + tx * 8 + 4];
  float bv[8] = {bb0.x, bb0.y, bb0.z, bb0.w, bb1.x, bb1.y, bb1.z, bb1.w};
#pragma unroll
  for (int i = 0; i < 8; ++i) {
    int g = rowbase + ty * 8 + i;
    if (g < n) {
      float o[8];
#pragma unroll
      for (int j = 0; j < 8; ++j) o[j] = fmaxf(acc[i][j] + bv[j], 0.f);
      float* ph = h + (size_t)g * 128 + tx * 8;
      *(float4*)(ph) = make_float4(o[0], o[1], o[2], o[3]);
      *(float4*)(ph + 4) = make_float4(o[4], o[5], o[6], o[7]);
    }
  }
}

// ---------------- GEMM2: plane += h_chunk @ W2[cbase:cbase+128, :] (+ b2 on first) ----------

__global__ __launch_bounds__(256) void k_gemm2(const float* __restrict__ h,
                                               const float* __restrict__ w2,
                                               const float* __restrict__ b2,
                                               float* __restrict__ plane, int n, int cbase,
                                               int first) {
  __shared__ float hs[64][132];
  __shared__ float w2s[128][64];
  int tid = threadIdx.x;
  int rowbase = blockIdx.x * 64;
  {
    int r = tid >> 2, q = (tid & 3) * 32;
    int g = rowbase + r;
    if (g < n) {
      const float* ph = h + (size_t)g * 128 + q;
#pragma unroll
      for (int i = 0; i < 8; ++i) *(float4*)&hs[r][q + i * 4] = *(const float4*)(ph + i * 4);
    } else {
#pragma unroll
      for (int i = 0; i < 32; ++i) hs[r][q + i] = 0.f;
    }
    int k = tid >> 1, half = (tid & 1) * 32;
    const float* pw = w2 + (size_t)(cbase + k) * GOUT_DIM + half;
#pragma unroll
    for (int i = 0; i < 8; ++i) *(float4*)&w2s[k][half + i * 4] = *(const float4*)(pw + i * 4);
  }
  __syncthreads();

  int trow = tid >> 2, tc = (tid & 3) * 16;
  float acc[16] = {};
  for (int k = 0; k < 128; ++k) {
    float hv = hs[trow][k];
#pragma unroll
    for (int j4 = 0; j4 < 4; ++j4) {
      float4 w = *(const float4*)&w2s[k][tc + j4 * 4];
      acc[j4 * 4 + 0] = fmaf(hv, w.x, acc[j4 * 4 + 0]);
      acc[j4 * 4 + 1] = fmaf(hv, w.y, acc[j4 * 4 + 1]);
      acc[j4 * 4 + 2] = fmaf(hv, w.z, acc[j4 * 4 + 2]);
      acc[j4 * 4 + 3] = fmaf(hv, w.w, acc[j4 * 4 + 3]);
    }
  }
  int g = rowbase + trow;
  if (g < n) {
    float* pp = plane + (size_t)g * GOUT_DIM + tc;
    if (first) {
#pragma unroll
      for (int j4 = 0; j4 < 4; ++j4) {
        float4 b = *(const float4*)&b2[tc + j4 * 4];
        float4 o = make_float4(acc[j4 * 4 + 0] + b.x, acc[j4 * 4 + 1] + b.y,
                               acc[j4 * 4 + 2] + b.z, acc[j4 * 4 + 3] + b.w);
        *(float4*)(pp + j4 * 4) = o;
      }
    } else {
#pragma unroll
      for (int j4 = 0; j4 < 4; ++j4) {
        float4 o = *(const float4*)(pp + j4 * 4);
        o.x += acc[j4 * 4 + 0];
        o.y += acc[j4 * 4 + 1];
        o.z += acc[j4 * 4 + 2];
        o.w += acc[j4 * 4 + 3];
        *(float4*)(pp + j4 * 4) = o;
      }
    }
  }
}

// ---------------- combine init: out = sigmoid(h0 . s) * h0 ----------------

__global__ void k_combine(const float* __restrict__ h0, const float* __restrict__ s,
                          float* __restrict__ out, int n) {
  int wave = (int)((blockIdx.x * blockDim.x + threadIdx.x) >> 6);
  int lane = threadIdx.x & 63;
  if (wave >= n) return;
  float v = h0[(size_t)wave * GOUT_DIM + lane];
  float dot = v * s[lane];
#pragma unroll
  for (int off = 32; off; off >>= 1) dot += __shfl_xor(dot, off);
  float sig = 1.f / (1.f + __expf(-dot));
  out[(size_t)wave * GOUT_DIM + lane] = sig * v;
}

// ---------------- SPMM hop: hout[r] = sum_e w*hin[col]; out += sigmoid(hout.s)*hout --------

__global__ void k_spmm(const int* __restrict__ rp, const int* __restrict__ cs,
                       const float* __restrict__ wsrt, const float* __restrict__ hin,
                       float* __restrict__ hout, const float* __restrict__ s,
                       float* __restrict__ out, int n) {
  int wave = (int)((blockIdx.x * blockDim.x + threadIdx.x) >> 6);
  int lane = threadIdx.x & 63;
  if (wave >= n) return;
  int e0 = __builtin_amdgcn_readfirstlane(rp[wave]);
  int e1 = __builtin_amdgcn_readfirstlane(rp[wave + 1]);
  float acc = 0.f;
  int e = e0;
  for (; e + 2 <= e1; e += 2) {
    int c0 = cs[e], c1 = cs[e + 1];
    float w0 = wsrt[e], w1 = wsrt[e + 1];
    float v0 = hin[(size_t)c0 * GOUT_DIM + lane];
    float v1 = hin[(size_t)c1 * GOUT_DIM + lane];
    acc = fmaf(w0, v0, acc);
    acc = fmaf(w1, v1, acc);
  }
  if (e < e1) {
    int c0 = cs[e];
    float w0 = wsrt[e];
    acc = fmaf(w0, hin[(size_t)c0 * GOUT_DIM + lane], acc);
  }
  hout[(size_t)wave * GOUT_DIM + lane] = acc;
  float dot = acc * s[lane];
#pragma unroll
  for (int off = 32; off; off >>= 1) dot += __shfl_xor(dot, off);
  float sig = 1.f / (1.f + __expf(-dot));
  out[(size_t)wave * GOUT_DIM + lane] += sig * acc;
}

// ---------------- launch ----------------

static inline char* align256(char* p) {
  return (char*)(((uintptr_t)p + 255) & ~(uintptr_t)255);
}

extern "C" void kernel_launch(void* const* d_in, const int* in_sizes, int n_in,
                              void* d_out, int out_size, void* d_ws, size_t ws_size,
                              hipStream_t stream) {
  const float* x = (const float*)d_in[0];
  const int* row = (const int*)d_in[1];
  const int* col = (const int*)d_in[2];
  const float* ew = (const float*)d_in[3];
  const float* W1 = (const float*)d_in[4];
  const float* b1 = (const float*)d_in[5];
  const float* W2 = (const float*)d_in[6];
  const float* b2 = (const float*)d_in[7];
  const float* s = (const float*)d_in[8];
  float* out = (float*)d_out;

  int N = in_sizes[0] / GIN_DIM;
  int E = in_sizes[1];

  char* w = (char*)d_ws;
  float* h_chunk = (float*)w;  w = align256(w + (size_t)N * 128 * sizeof(float));
  float* planeA = (float*)w;   w = align256(w + (size_t)N * GOUT_DIM * sizeof(float));
  float* planeB = (float*)w;   w = align256(w + (size_t)N * GOUT_DIM * sizeof(float));
  int* rp = (int*)w;           w = align256(w + ((size_t)N + 1) * sizeof(int));
  int* nxt = (int*)w;          w = align256(w + (size_t)N * sizeof(int));
  int* cs = (int*)w;           w = align256(w + (size_t)E * sizeof(int));
  float* wsrt = (float*)w;     w = align256(w + (size_t)E * sizeof(float));

  // CSR build
  hipMemsetAsync(rp, 0, ((size_t)N + 1) * sizeof(int), stream);
  k_count<<<(E + 255) / 256, 256, 0, stream>>>(row, rp, E);
  k_scan<<<1, 1024, 0, stream>>>(rp, nxt, N);
  k_scatter<<<(E + 255) / 256, 256, 0, stream>>>(row, col, ew, nxt, cs, wsrt, E);

  // dense front: plane0 = relu(x@W1+b1)@W2 + b2, chunked over hidden dim
  for (int c = 0; c < 4; ++c) {
    k_gemm1<<<(N + 127) / 128, 256, 0, stream>>>(x, W1, b1, h_chunk, N, c * 128);
    k_gemm2<<<(N + 63) / 64, 256, 0, stream>>>(h_chunk, W2, b2, planeA, N, c * 128, c == 0);
  }

  // out = sigmoid(h0.s)*h0
  k_combine<<<(N + 3) / 4, 256, 0, stream>>>(planeA, s, out, N);

  // 10 hops, online accumulation into out
  const float* hin = planeA;
  float* hout = planeB;
  for (int k = 0; k < GHOP; ++k) {
    k_spmm<<<(N + 3) / 4, 256, 0, stream>>>(rp, cs, wsrt, hin, hout, s, out, N);
    float* t = (float*)hin;
    hin = hout;
    hout = t;
  }
}

// Round 2
// 2364.929 us; speedup vs baseline: 1.3949x; 1.3949x over previous
//
#include <hip/hip_runtime.h>
#include <math.h>
#include <stdint.h>

#define GIN_DIM 512
#define GHID_DIM 512
#define GOUT_DIM 64
#define GHOP 10

typedef __attribute__((ext_vector_type(8))) short short8;
typedef __attribute__((ext_vector_type(4))) float f32x4;

__device__ __forceinline__ unsigned f2bf_bits(float f) {
  unsigned u = __float_as_uint(f);
  return (u + 0x7FFFu + ((u >> 16) & 1u)) >> 16;
}
__device__ __forceinline__ float bf2f_bits(unsigned h) { return __uint_as_float(h << 16); }
__device__ __forceinline__ int slot_sw(int r, int o) { return (o ^ r) & 7; }

// ---------------- CSR build ----------------

__global__ void k_count(const int* __restrict__ row, int* __restrict__ cnt, int E) {
  int e = blockIdx.x * blockDim.x + threadIdx.x;
  if (e < E) atomicAdd(&cnt[row[e]], 1);
}

// pass1: per-block (1024 elems) reduce
__global__ __launch_bounds__(256) void k_scan1(const int* __restrict__ cnt,
                                               int* __restrict__ bsum, int n) {
  __shared__ int sd[256];
  int b = blockIdx.x, t = threadIdx.x;
  int base = b * 1024 + t * 4;
  int s = 0;
#pragma unroll
  for (int j = 0; j < 4; ++j) {
    int i = base + j;
    if (i < n) s += cnt[i];
  }
  sd[t] = s;
  __syncthreads();
  for (int off = 128; off; off >>= 1) {
    if (t < off) sd[t] += sd[t + off];
    __syncthreads();
  }
  if (t == 0) bsum[b] = sd[0];
}

// pass2: exclusive scan of block sums (nb <= 128), writes rp[n]=total
__global__ __launch_bounds__(128) void k_scan2(int* __restrict__ bsum, int* __restrict__ rp,
                                               int nb, int n) {
  __shared__ int sd[128];
  int t = threadIdx.x;
  int v = (t < nb) ? bsum[t] : 0;
  int incl = v;
  sd[t] = incl;
  __syncthreads();
  for (int off = 1; off < 128; off <<= 1) {
    int add = (t >= off) ? sd[t - off] : 0;
    __syncthreads();
    incl += add;
    sd[t] = incl;
    __syncthreads();
  }
  if (t < nb) bsum[t] = incl - v;  // exclusive
  if (t == nb - 1) rp[n] = incl;   // total
}

// pass3: block-local scan + apply, write rp and nxt
__global__ __launch_bounds__(256) void k_scan3(const int* __restrict__ cnt,
                                               const int* __restrict__ bsum,
                                               int* __restrict__ rp, int* __restrict__ nxt,
                                               int n) {
  __shared__ int sd[256];
  int b = blockIdx.x, t = threadIdx.x;
  int base = b * 1024 + t * 4;
  int v[4];
  int s = 0;
#pragma unroll
  for (int j = 0; j < 4; ++j) {
    int i = base + j;
    v[j] = (i < n) ? cnt[i] : 0;
    s += v[j];
  }
  int incl = s;
  sd[t] = incl;
  __syncthreads();
  for (int off = 1; off < 256; off <<= 1) {
    int add = (t >= off) ? sd[t - off] : 0;
    __syncthreads();
    incl += add;
    sd[t] = incl;
    __syncthreads();
  }
  int run = incl - s + bsum[b];
#pragma unroll
  for (int j = 0; j < 4; ++j) {
    int i = base + j;
    if (i < n) {
      rp[i] = run;
      nxt[i] = run;
      run += v[j];
    }
  }
}

__global__ void k_scatter(const int* __restrict__ row, const int* __restrict__ col,
                          const float* __restrict__ ew, int* __restrict__ nxt,
                          int2* __restrict__ epk, int E) {
  int e = blockIdx.x * blockDim.x + threadIdx.x;
  if (e < E) {
    int r = row[e];
    int p = atomicAdd(&nxt[r], 1);
    epk[p] = make_int2(col[e], __float_as_int(ew[e]));
  }
}

// ---------------- W1 transpose + bf16 hi/lo split: W1[512k][512n] -> W1t[n][k] ----------------

__global__ __launch_bounds__(1024) void k_w1t(const float* __restrict__ w1,
                                              ushort* __restrict__ hi,
                                              ushort* __restrict__ lo) {
  __shared__ float t[32][33];
  int bx = blockIdx.x;  // n tile
  int by = blockIdx.y;  // k tile
  int tx = threadIdx.x & 31, ty = threadIdx.x >> 5;
  t[ty][tx] = w1[(size_t)(by * 32 + ty) * GHID_DIM + bx * 32 + tx];
  __syncthreads();
  float v = t[tx][ty];  // = w1[by*32+tx][bx*32+ty]
  unsigned h = f2bf_bits(v);
  unsigned l = f2bf_bits(v - bf2f_bits(h));
  size_t o = (size_t)(bx * 32 + ty) * GIN_DIM + by * 32 + tx;
  hi[o] = (ushort)h;
  lo[o] = (ushort)l;
}

// ---------------- GEMM1 (split-bf16 MFMA): h_chunk = relu(x @ W1[:,cbase:+128] + b1) -------
// BM=128, BN=128, BK=64, 256 threads (4 waves, 2x2), wave-tile 64x64 (4x4 frags 16x16x32).

__global__ __launch_bounds__(256) void k_gemm1(const float* __restrict__ x,
                                               const ushort* __restrict__ w1h,
                                               const ushort* __restrict__ w1l,
                                               const float* __restrict__ b1,
                                               float* __restrict__ h, int n, int cbase) {
  __shared__ __align__(16) ushort Ah[128 * 64];
  __shared__ __align__(16) ushort Al[128 * 64];
  __shared__ __align__(16) ushort Bh[128 * 64];
  __shared__ __align__(16) ushort Bl[128 * 64];
  int tid = threadIdx.x;
  int wave = tid >> 6, lane = tid & 63;
  int wm = wave >> 1, wn = wave & 1;
  int fr = lane & 15, fq = lane >> 4;
  int rowbase = blockIdx.x * 128;

  f32x4 acc[4][4];
#pragma unroll
  for (int m = 0; m < 4; ++m)
#pragma unroll
    for (int q = 0; q < 4; ++q) acc[m][q] = (f32x4)(0.f);

  int sr = tid >> 1;          // staged row / B col 0..127
  int sk = (tid & 1) * 32;    // k offset within BK tile

  for (int ks = 0; ks < GIN_DIM; ks += 64) {
    // ---- stage A from x (fp32 -> hi/lo bf16), swizzled octets ----
    {
      int gr = rowbase + sr;
      float vals[32];
      if (gr < n) {
        const float* px = x + (size_t)gr * GIN_DIM + ks + sk;
#pragma unroll
        for (int q = 0; q < 8; ++q) {
          float4 v = *(const float4*)(px + q * 4);
          vals[q * 4 + 0] = v.x;
          vals[q * 4 + 1] = v.y;
          vals[q * 4 + 2] = v.z;
          vals[q * 4 + 3] = v.w;
        }
      } else {
#pragma unroll
        for (int q = 0; q < 32; ++q) vals[q] = 0.f;
      }
#pragma unroll
      for (int o4 = 0; o4 < 4; ++o4) {
        short8 vh, vl;
#pragma unroll
        for (int j = 0; j < 8; ++j) {
          float a = vals[o4 * 8 + j];
          unsigned hb = f2bf_bits(a);
          float r = a - bf2f_bits(hb);
          unsigned lb = f2bf_bits(r);
          vh[j] = (short)hb;
          vl[j] = (short)lb;
        }
        int oct = (sk >> 3) + o4;
        int off = sr * 64 + slot_sw(sr, oct) * 8;
        *reinterpret_cast<short8*>(&Ah[off]) = vh;
        *reinterpret_cast<short8*>(&Al[off]) = vl;
      }
    }
    // ---- stage B from pre-split W1t rows (bf16, contiguous) ----
    {
      const ushort* ph = w1h + (size_t)(cbase + sr) * GIN_DIM + ks + sk;
      const ushort* pl = w1l + (size_t)(cbase + sr) * GIN_DIM + ks + sk;
#pragma unroll
      for (int o4 = 0; o4 < 4; ++o4) {
        short8 vh = *reinterpret_cast<const short8*>(ph + o4 * 8);
        short8 vl = *reinterpret_cast<const short8*>(pl + o4 * 8);
        int oct = (sk >> 3) + o4;
        int off = sr * 64 + slot_sw(sr, oct) * 8;
        *reinterpret_cast<short8*>(&Bh[off]) = vh;
        *reinterpret_cast<short8*>(&Bl[off]) = vl;
      }
    }
    __syncthreads();

#pragma unroll
    for (int kk = 0; kk < 2; ++kk) {
      int koct = kk * 4 + fq;
      short8 bH[4], bL[4];
#pragma unroll
      for (int q = 0; q < 4; ++q) {
        int c = wn * 64 + q * 16 + fr;
        int off = c * 64 + slot_sw(c, koct) * 8;
        bH[q] = *reinterpret_cast<const short8*>(&Bh[off]);
        bL[q] = *reinterpret_cast<const short8*>(&Bl[off]);
      }
#pragma unroll
      for (int m = 0; m < 4; ++m) {
        int r = wm * 64 + m * 16 + fr;
        int off = r * 64 + slot_sw(r, koct) * 8;
        short8 aH = *reinterpret_cast<const short8*>(&Ah[off]);
        short8 aL = *reinterpret_cast<const short8*>(&Al[off]);
#pragma unroll
        for (int q = 0; q < 4; ++q) {
          f32x4 t = acc[m][q];
          t = __builtin_amdgcn_mfma_f32_16x16x32_bf16(aH, bL[q], t, 0, 0, 0);
          t = __builtin_amdgcn_mfma_f32_16x16x32_bf16(aL, bH[q], t, 0, 0, 0);
          t = __builtin_amdgcn_mfma_f32_16x16x32_bf16(aH, bH[q], t, 0, 0, 0);
          acc[m][q] = t;
        }
      }
    }
    __syncthreads();
  }

  // ---- epilogue: bias + relu, store fp32 h_chunk [n][128] ----
#pragma unroll
  for (int m = 0; m < 4; ++m) {
#pragma unroll
    for (int q = 0; q < 4; ++q) {
      int coll = wn * 64 + q * 16 + fr;
      float bias = b1[cbase + coll];
#pragma unroll
      for (int j = 0; j < 4; ++j) {
        int rowl = wm * 64 + m * 16 + fq * 4 + j;
        int grow = rowbase + rowl;
        if (grow < n) h[(size_t)grow * 128 + coll] = fmaxf(acc[m][q][j] + bias, 0.f);
      }
    }
  }
}

// ---------------- GEMM2: plane += h_chunk @ W2[cbase:cbase+128, :] (+ b2 on first) ----------

__global__ __launch_bounds__(256) void k_gemm2(const float* __restrict__ h,
                                               const float* __restrict__ w2,
                                               const float* __restrict__ b2,
                                               float* __restrict__ plane, int n, int cbase,
                                               int first) {
  __shared__ float hs[64][132];
  __shared__ float w2s[128][64];
  int tid = threadIdx.x;
  int rowbase = blockIdx.x * 64;
  {
    int r = tid >> 2, q = (tid & 3) * 32;
    int g = rowbase + r;
    if (g < n) {
      const float* ph = h + (size_t)g * 128 + q;
#pragma unroll
      for (int i = 0; i < 8; ++i) *(float4*)&hs[r][q + i * 4] = *(const float4*)(ph + i * 4);
    } else {
#pragma unroll
      for (int i = 0; i < 32; ++i) hs[r][q + i] = 0.f;
    }
    int k = tid >> 1, half = (tid & 1) * 32;
    const float* pw = w2 + (size_t)(cbase + k) * GOUT_DIM + half;
#pragma unroll
    for (int i = 0; i < 8; ++i) *(float4*)&w2s[k][half + i * 4] = *(const float4*)(pw + i * 4);
  }
  __syncthreads();

  int trow = tid >> 2, tc = (tid & 3) * 16;
  float acc[16] = {};
  for (int k = 0; k < 128; ++k) {
    float hv = hs[trow][k];
#pragma unroll
    for (int j4 = 0; j4 < 4; ++j4) {
      float4 w = *(const float4*)&w2s[k][tc + j4 * 4];
      acc[j4 * 4 + 0] = fmaf(hv, w.x, acc[j4 * 4 + 0]);
      acc[j4 * 4 + 1] = fmaf(hv, w.y, acc[j4 * 4 + 1]);
      acc[j4 * 4 + 2] = fmaf(hv, w.z, acc[j4 * 4 + 2]);
      acc[j4 * 4 + 3] = fmaf(hv, w.w, acc[j4 * 4 + 3]);
    }
  }
  int g = rowbase + trow;
  if (g < n) {
    float* pp = plane + (size_t)g * GOUT_DIM + tc;
    if (first) {
#pragma unroll
      for (int j4 = 0; j4 < 4; ++j4) {
        float4 b = *(const float4*)&b2[tc + j4 * 4];
        float4 o = make_float4(acc[j4 * 4 + 0] + b.x, acc[j4 * 4 + 1] + b.y,
                               acc[j4 * 4 + 2] + b.z, acc[j4 * 4 + 3] + b.w);
        *(float4*)(pp + j4 * 4) = o;
      }
    } else {
#pragma unroll
      for (int j4 = 0; j4 < 4; ++j4) {
        float4 o = *(const float4*)(pp + j4 * 4);
        o.x += acc[j4 * 4 + 0];
        o.y += acc[j4 * 4 + 1];
        o.z += acc[j4 * 4 + 2];
        o.w += acc[j4 * 4 + 3];
        *(float4*)(pp + j4 * 4) = o;
      }
    }
  }
}

// ---------------- combine init: out = sigmoid(h0 . s) * h0 ----------------

__global__ void k_combine(const float* __restrict__ h0, const float* __restrict__ s,
                          float* __restrict__ out, int n) {
  int wave = (int)((blockIdx.x * blockDim.x + threadIdx.x) >> 6);
  int lane = threadIdx.x & 63;
  if (wave >= n) return;
  float v = h0[(size_t)wave * GOUT_DIM + lane];
  float dot = v * s[lane];
#pragma unroll
  for (int off = 32; off; off >>= 1) dot += __shfl_xor(dot, off);
  float sig = 1.f / (1.f + __expf(-dot));
  out[(size_t)wave * GOUT_DIM + lane] = sig * v;
}

// ---------------- SPMM hop ----------------

__global__ void k_spmm(const int* __restrict__ rp, const int2* __restrict__ epk,
                       const float* __restrict__ hin, float* __restrict__ hout,
                       const float* __restrict__ s, float* __restrict__ out, int n) {
  int wave = (int)((blockIdx.x * blockDim.x + threadIdx.x) >> 6);
  int lane = threadIdx.x & 63;
  if (wave >= n) return;
  int e0 = __builtin_amdgcn_readfirstlane(rp[wave]);
  int e1 = __builtin_amdgcn_readfirstlane(rp[wave + 1]);
  float sl = s[lane];
  float acc = 0.f, acc2 = 0.f;
  int e = e0;
  for (; e + 4 <= e1; e += 4) {
    int2 p0 = epk[e], p1 = epk[e + 1], p2 = epk[e + 2], p3 = epk[e + 3];
    float v0 = hin[(size_t)p0.x * GOUT_DIM + lane];
    float v1 = hin[(size_t)p1.x * GOUT_DIM + lane];
    float v2 = hin[(size_t)p2.x * GOUT_DIM + lane];
    float v3 = hin[(size_t)p3.x * GOUT_DIM + lane];
    acc = fmaf(__int_as_float(p0.y), v0, acc);
    acc2 = fmaf(__int_as_float(p1.y), v1, acc2);
    acc = fmaf(__int_as_float(p2.y), v2, acc);
    acc2 = fmaf(__int_as_float(p3.y), v3, acc2);
  }
  for (; e < e1; ++e) {
    int2 p = epk[e];
    acc = fmaf(__int_as_float(p.y), hin[(size_t)p.x * GOUT_DIM + lane], acc);
  }
  acc += acc2;
  hout[(size_t)wave * GOUT_DIM + lane] = acc;
  float dot = acc * sl;
#pragma unroll
  for (int off = 32; off; off >>= 1) dot += __shfl_xor(dot, off);
  float sig = 1.f / (1.f + __expf(-dot));
  out[(size_t)wave * GOUT_DIM + lane] += sig * acc;
}

// ---------------- launch ----------------

static inline char* align256(char* p) {
  return (char*)(((uintptr_t)p + 255) & ~(uintptr_t)255);
}

extern "C" void kernel_launch(void* const* d_in, const int* in_sizes, int n_in,
                              void* d_out, int out_size, void* d_ws, size_t ws_size,
                              hipStream_t stream) {
  const float* x = (const float*)d_in[0];
  const int* row = (const int*)d_in[1];
  const int* col = (const int*)d_in[2];
  const float* ew = (const float*)d_in[3];
  const float* W1 = (const float*)d_in[4];
  const float* b1 = (const float*)d_in[5];
  const float* W2 = (const float*)d_in[6];
  const float* b2 = (const float*)d_in[7];
  const float* s = (const float*)d_in[8];
  float* out = (float*)d_out;

  int N = in_sizes[0] / GIN_DIM;
  int E = in_sizes[1];

  char* w = (char*)d_ws;
  float* h_chunk = (float*)w; w = align256(w + (size_t)N * 128 * sizeof(float));
  float* planeA = (float*)w;  w = align256(w + (size_t)N * GOUT_DIM * sizeof(float));
  float* planeB = (float*)w;  w = align256(w + (size_t)N * GOUT_DIM * sizeof(float));
  int* cnt = (int*)w;         w = align256(w + (size_t)N * sizeof(int));
  int* rp = (int*)w;          w = align256(w + ((size_t)N + 1) * sizeof(int));
  int* nxt = (int*)w;         w = align256(w + (size_t)N * sizeof(int));
  int* bsum = (int*)w;        w = align256(w + 256 * sizeof(int));
  int2* epk = (int2*)w;       w = align256(w + (size_t)E * sizeof(int2));
  ushort* w1h = (ushort*)w;   w = align256(w + (size_t)GIN_DIM * GHID_DIM * sizeof(ushort));
  ushort* w1l = (ushort*)w;   w = align256(w + (size_t)GIN_DIM * GHID_DIM * sizeof(ushort));

  int nb = (N + 1023) / 1024;  // 98

  // CSR build
  hipMemsetAsync(cnt, 0, (size_t)N * sizeof(int), stream);
  k_count<<<(E + 255) / 256, 256, 0, stream>>>(row, cnt, E);
  k_scan1<<<nb, 256, 0, stream>>>(cnt, bsum, N);
  k_scan2<<<1, 128, 0, stream>>>(bsum, rp, nb, N);
  k_scan3<<<nb, 256, 0, stream>>>(cnt, bsum, rp, nxt, N);
  k_scatter<<<(E + 255) / 256, 256, 0, stream>>>(row, col, ew, nxt, epk, E);

  // W1 transpose + bf16 split
  k_w1t<<<dim3(16, 16), 1024, 0, stream>>>(W1, w1h, w1l);

  // dense front: planeA = relu(x@W1+b1)@W2 + b2, chunked over hidden dim
  for (int c = 0; c < 4; ++c) {
    k_gemm1<<<(N + 127) / 128, 256, 0, stream>>>(x, w1h, w1l, b1, h_chunk, N, c * 128);
    k_gemm2<<<(N + 63) / 64, 256, 0, stream>>>(h_chunk, W2, b2, planeA, N, c * 128, c == 0);
  }

  // out = sigmoid(h0.s)*h0
  k_combine<<<(N + 3) / 4, 256, 0, stream>>>(planeA, s, out, N);

  // 10 hops, online accumulation into out
  const float* hin = planeA;
  float* hout = planeB;
  for (int k = 0; k < GHOP; ++k) {
    k_spmm<<<(N + 3) / 4, 256, 0, stream>>>(rp, epk, hin, hout, s, out, N);
    float* t = (float*)hin;
    hin = hout;
    hout = t;
  }
}